// Round 13
// baseline (9282.879 us; speedup 1.0000x reference)
//
#include <hip/hip_runtime.h>
#include <hip/hip_bf16.h>

#define C 192
#define T 4096
#define L 16
#define BATCH 16
#define NT 128         // t-positions per block
#define XR 136         // x tile rows incl. halo 4+4
#define CPAD 200       // padded channel stride in LDS (halfs) -> 400B rows

#define CONV_TAP_STRIDE 73728   // elems: 24*6*512
#define MT_STRIDE       3072    // 6*512
#define ICC_STRIDE      512

typedef __attribute__((ext_vector_type(8))) _Float16 half8;
typedef __attribute__((ext_vector_type(4))) _Float16 half4;
typedef __attribute__((ext_vector_type(4))) float f32x4;

__device__ __forceinline__ float gatefn(float x1, float x2) {
    float ax = fabsf(x1);
    float e  = __expf(-2.f * ax);
    float th = __builtin_copysignf((1.f - e) / (1.f + e), x1);
    float sg = 1.f / (1.f + __expf(-x2));
    return th * sg;
}

// ---- weight pre-format, single fp16 plane, MFMA A-frag order ----
__global__ __launch_bounds__(256)
void fmt_win(const float* __restrict__ W, _Float16* __restrict__ dst, int total) {
    int gid = blockIdx.x * 256 + threadIdx.x;
    if (gid >= total) return;
    int lane = gid & 63; int r = gid >> 6;
    int icc = r % 6; r /= 6;
    int mt  = r % 24; r /= 24;
    int tap = r % 5;  int l = r / 5;
    int oc  = mt * 16 + (lane & 15);
    int ic0 = icc * 32 + (lane >> 4) * 8;
    const float* s = W + ((size_t)((l * 384 + oc) * 192 + ic0)) * 5 + tap;
    half8 v;
    #pragma unroll
    for (int i = 0; i < 8; ++i) v[i] = (_Float16)s[(size_t)i * 5];
    *reinterpret_cast<half8*>(dst + (size_t)gid * 8) = v;
}

__global__ __launch_bounds__(256)
void fmt_w11(const float* __restrict__ W, _Float16* __restrict__ dst, int mtc, int total) {
    int gid = blockIdx.x * 256 + threadIdx.x;
    if (gid >= total) return;
    int lane = gid & 63; int r = gid >> 6;
    int icc = r % 6; r /= 6;
    int mt  = r % mtc; int l = r / mtc;
    int oc  = mt * 16 + (lane & 15);
    int ic0 = icc * 32 + (lane >> 4) * 8;
    const float* s = W + (size_t)(l * (mtc * 16) + oc) * 192 + ic0;
    half8 v;
    #pragma unroll
    for (int i = 0; i < 8; ++i) v[i] = (_Float16)s[i];
    *reinterpret_cast<half8*>(dst + (size_t)gid * 8) = v;
}

// ---- one-time transpose+split: x fp32 [b][c][t] -> fp16 hi/lo planes [b][t][c] ----
__global__ __launch_bounds__(256)
void xpose(const float* __restrict__ x, _Float16* __restrict__ xh, _Float16* __restrict__ xl)
{
    __shared__ float tile[C][65];
    const int t0 = blockIdx.x * 64;
    const int b  = blockIdx.y;
    const float* xg = x + (size_t)b * C * T;
    for (int idx = threadIdx.x; idx < C * 16; idx += 256) {
        int ch = idx & 15, c = idx >> 4;
        f32x4 v = *reinterpret_cast<const f32x4*>(xg + (size_t)c * T + t0 + ch * 4);
        #pragma unroll
        for (int q = 0; q < 4; ++q) tile[c][ch * 4 + q] = v[q];
    }
    __syncthreads();
    for (int idx = threadIdx.x; idx < 64 * 24; idx += 256) {
        int cc = idx % 24, t = idx / 24;
        half8 h8, l8;
        #pragma unroll
        for (int i = 0; i < 8; ++i) {
            float v = tile[cc * 8 + i][t];
            _Float16 h = (_Float16)v;
            h8[i] = h;
            l8[i] = (_Float16)(v - (float)h);
        }
        size_t off = (size_t)b * T * C + (size_t)(t0 + t) * C + cc * 8;
        *reinterpret_cast<half8*>(xh + off) = h8;
        *reinterpret_cast<half8*>(xl + off) = l8;
    }
}

// ---- fused WaveNet layer, single-pass fp16 MFMA, NT=128 ----
// 8 waves: wm=wid&3 (6 mt each), wn=wid>>2 (2 nt-halves, p=4 subtiles).
// 54.4 KB LDS (hi plane) -> 2 blocks/CU resident (grid = exactly 2/CU).
// launch_bounds(512,4): pin VGPR<=128 so both blocks stay resident.
template<bool FIRST, bool LAST>
__global__ __launch_bounds__(512, 4)
void wnet_layer(const _Float16* __restrict__ xhin, const _Float16* __restrict__ xlin,
                _Float16* __restrict__ xhout, _Float16* __restrict__ xlout,
                const float* __restrict__ mask,
                const _Float16* __restrict__ wc,   // conv weights fp16
                const float* __restrict__ bc,
                const _Float16* __restrict__ wr,   // 1x1 weights fp16
                const float* __restrict__ br,
                float* __restrict__ o)
{
    __shared__ __align__(16) _Float16 xhi[XR * CPAD];   // 54,400 B

    const int tid = threadIdx.x;
    const int t0  = blockIdx.x * NT;
    const int b   = blockIdx.y;

    // ---- stage hi plane: pure 16B vector copies ----
    {
        const _Float16* gh = xhin + (size_t)b * T * C;
        for (int idx = tid; idx < XR * 24; idx += 512) {
            int chunk = idx % 24;
            int r     = idx / 24;
            int t = t0 - 4 + r;
            half8 v = {};
            if (t >= 0 && t < T)
                v = *reinterpret_cast<const half8*>(gh + (size_t)t * C + chunk * 8);
            *reinterpret_cast<half8*>(&xhi[r * CPAD + chunk * 8]) = v;
        }
    }
    __syncthreads();

    const int lane = tid & 63;
    const int wid  = tid >> 6;
    const int wm   = wid & 3;
    const int wn   = wid >> 2;      // 0..1
    const int col  = lane & 15;
    const int sg   = lane >> 4;

    int wbase[6];
    #pragma unroll
    for (int q = 0; q < 6; ++q) {
        int h = q / 3, j = q % 3;
        int mt = h * 12 + wm * 3 + j;
        wbase[q] = mt * MT_STRIDE + lane * 8;
    }

    // ---- conv K5, single pass, dbuf weight pipeline ----
    f32x4 acc[3][2][4];
    #pragma unroll
    for (int j = 0; j < 3; ++j)
    #pragma unroll
    for (int h = 0; h < 2; ++h) {
        f32x4 bv = *reinterpret_cast<const f32x4*>(bc + (h * 12 + wm * 3 + j) * 16 + sg * 4);
        #pragma unroll
        for (int p = 0; p < 4; ++p) acc[j][h][p] = bv;
    }

    half8 hA[6], hB[6];
    #pragma unroll
    for (int q = 0; q < 6; ++q)
        hA[q] = *reinterpret_cast<const half8*>(wc + wbase[q]);   // (tap0,icc0)

    auto convstep = [&](int icc, half8 (&curH)[6], half8 (&nxtH)[6],
                        size_t tapoff, size_t ntapoff, int tap) {
        const size_t coff = tapoff + (size_t)icc * ICC_STRIDE;
        const size_t noff = (icc == 5) ? ntapoff : coff + ICC_STRIDE;
        #pragma unroll
        for (int q = 0; q < 6; ++q)
            nxtH[q] = *reinterpret_cast<const half8*>(wc + noff + wbase[q]);
        half8 bh[4];
        #pragma unroll
        for (int p = 0; p < 4; ++p) {
            int off = ((wn * 4 + p) * 16 + col + tap + 2) * CPAD + icc * 32 + sg * 8;
            bh[p] = *reinterpret_cast<const half8*>(&xhi[off]);
        }
        __builtin_amdgcn_sched_barrier(0);
        __builtin_amdgcn_s_setprio(1);
        #pragma unroll
        for (int h = 0; h < 2; ++h)
        #pragma unroll
        for (int j = 0; j < 3; ++j)
        #pragma unroll
        for (int p = 0; p < 4; ++p)
            acc[j][h][p] = __builtin_amdgcn_mfma_f32_16x16x32_f16(
                curH[h * 3 + j], bh[p], acc[j][h][p], 0, 0, 0);
        __builtin_amdgcn_s_setprio(0);
    };

    for (int tap = 0; tap < 5; ++tap) {
        const size_t tapoff  = (size_t)tap * CONV_TAP_STRIDE;
        const size_t ntapoff = (size_t)(tap < 4 ? tap + 1 : 4) * CONV_TAP_STRIDE;
        #pragma unroll
        for (int ih = 0; ih < 3; ++ih) {
            convstep(2 * ih,     hA, hB, tapoff, ntapoff, tap);
            convstep(2 * ih + 1, hB, hA, tapoff, ntapoff, tap);
        }
    }

    // ---- residual x-hi pre-read from LDS (before acts overwrite) ----
    half4 xresh[3][4];
    if constexpr (!LAST) {
        #pragma unroll
        for (int p = 0; p < 4; ++p) {
            const int row = (wn * 4 + p) * 16 + col + 4;
            #pragma unroll
            for (int j = 0; j < 3; ++j) {
                const int ch = (wm * 3 + j) * 16 + sg * 4;
                xresh[j][p] = *reinterpret_cast<const half4*>(&xhi[row * CPAD + ch]);
            }
        }
    }
    __syncthreads();   // conv + residual LDS reads done before acts overwrite

    // ---- gate -> acts fp16 (reuse xhi rows [0,NT)) ----
    #pragma unroll
    for (int j = 0; j < 3; ++j)
    #pragma unroll
    for (int p = 0; p < 4; ++p) {
        const int tt = (wn * 4 + p) * 16 + col;
        const int ch = (wm * 3 + j) * 16 + sg * 4;
        half4 av;
        #pragma unroll
        for (int i = 0; i < 4; ++i)
            av[i] = (_Float16)gatefn(acc[j][0][p][i], acc[j][1][p][i]);
        *reinterpret_cast<half4*>(&xhi[tt * CPAD + ch]) = av;
    }
    __syncthreads();

    // ---- 1x1 single pass, two sequential h-phases, dbuf pipeline ----
    const float* mb = mask + (size_t)b * T;
    float mv[4];
    #pragma unroll
    for (int p = 0; p < 4; ++p) mv[p] = mb[t0 + (wn * 4 + p) * 16 + col];

    constexpr int HN = LAST ? 1 : 2;
    #pragma unroll
    for (int h = 0; h < HN; ++h) {
        f32x4 a2[3][4];
        #pragma unroll
        for (int j = 0; j < 3; ++j) {
            f32x4 bv = *reinterpret_cast<const f32x4*>(br + (h * 12 + wm * 3 + j) * 16 + sg * 4);
            #pragma unroll
            for (int p = 0; p < 4; ++p) a2[j][p] = bv;
        }
        const int* wb = wbase + h * 3;

        half8 rA[3], rB[3];
        #pragma unroll
        for (int q = 0; q < 3; ++q)
            rA[q] = *reinterpret_cast<const half8*>(wr + wb[q]);   // icc=0

        auto r1step = [&](int icc, half8 (&cur)[3], half8 (&nxt)[3]) {
            const size_t noff = (size_t)(icc < 5 ? icc + 1 : 5) * ICC_STRIDE;
            #pragma unroll
            for (int q = 0; q < 3; ++q)
                nxt[q] = *reinterpret_cast<const half8*>(wr + noff + wb[q]);
            half8 bah[4];
            #pragma unroll
            for (int p = 0; p < 4; ++p) {
                int off = ((wn * 4 + p) * 16 + col) * CPAD + icc * 32 + sg * 8;
                bah[p] = *reinterpret_cast<const half8*>(&xhi[off]);
            }
            __builtin_amdgcn_sched_barrier(0);
            __builtin_amdgcn_s_setprio(1);
            #pragma unroll
            for (int j = 0; j < 3; ++j)
            #pragma unroll
            for (int p = 0; p < 4; ++p)
                a2[j][p] = __builtin_amdgcn_mfma_f32_16x16x32_f16(
                    cur[j], bah[p], a2[j][p], 0, 0, 0);
            __builtin_amdgcn_s_setprio(0);
        };

        #pragma unroll
        for (int ih = 0; ih < 3; ++ih) {
            r1step(2 * ih,     rA, rB);
            r1step(2 * ih + 1, rB, rA);
        }

        // ---- mini-epilogue for this phase ----
        #pragma unroll
        for (int p = 0; p < 4; ++p) {
            const int tt = (wn * 4 + p) * 16 + col;
            const int t  = t0 + tt;
            #pragma unroll
            for (int j = 0; j < 3; ++j) {
                const int ch = (wm * 3 + j) * 16 + sg * 4;
                if constexpr (LAST) {
                    float* op = o + ((size_t)b * C + ch) * T + t;
                    #pragma unroll
                    for (int i = 0; i < 4; ++i)
                        op[(size_t)i * T] = (op[(size_t)i * T] + a2[j][p][i]) * mv[p];
                } else if (h == 0) {
                    // residual x update: master = hi(LDS-preread) + lo(global)
                    size_t off = (size_t)b * T * C + (size_t)t * C + ch;
                    half4 xl4 = *reinterpret_cast<const half4*>(xlin + off);
                    half4 h4, l4;
                    #pragma unroll
                    for (int i = 0; i < 4; ++i) {
                        float xm = (float)xresh[j][p][i] + (float)xl4[i];
                        float nx = (xm + a2[j][p][i]) * mv[p];
                        _Float16 hh = (_Float16)nx;
                        h4[i] = hh;
                        l4[i] = (_Float16)(nx - (float)hh);
                    }
                    *reinterpret_cast<half4*>(xhout + off) = h4;
                    *reinterpret_cast<half4*>(xlout + off) = l4;
                } else {
                    float* op = o + ((size_t)b * C + ch) * T + t;
                    #pragma unroll
                    for (int i = 0; i < 4; ++i) {
                        if constexpr (FIRST) op[(size_t)i * T] = a2[j][p][i];
                        else                 op[(size_t)i * T] += a2[j][p][i];
                    }
                }
            }
        }
    }
}

#define WIN_STRIDE ((size_t)5 * 24 * 6 * 64 * 8)
#define WRS_STRIDE ((size_t)24 * 6 * 64 * 8)

extern "C" void kernel_launch(void* const* d_in, const int* in_sizes, int n_in,
                              void* d_out, int out_size, void* d_ws, size_t ws_size,
                              hipStream_t stream)
{
    const float* x      = (const float*)d_in[0];
    const float* mask   = (const float*)d_in[1];
    const float* W_in   = (const float*)d_in[2];
    const float* b_in   = (const float*)d_in[3];
    const float* W_rs   = (const float*)d_in[4];
    const float* b_rs   = (const float*)d_in[5];
    const float* W_last = (const float*)d_in[6];
    const float* b_last = (const float*)d_in[7];
    float* o = (float*)d_out;

    const size_t WIN_N = (size_t)L * WIN_STRIDE;
    const size_t WRS_N = (size_t)(L - 1) * WRS_STRIDE;
    const size_t WL_N  = (size_t)12 * 6 * 64 * 8;
    const size_t P     = (size_t)BATCH * T * C;      // plane elems
    _Float16* wc  = (_Float16*)d_ws;
    _Float16* wr  = wc + WIN_N;
    _Float16* wl  = wr + WRS_N;
    _Float16* xah = wl + WL_N;
    _Float16* xal = xah + P;
    _Float16* xbh = xal + P;
    _Float16* xbl = xbh + P;

    {
        int tw = (int)(L * 5 * 24 * 6 * 64);
        fmt_win<<<(tw + 255) / 256, 256, 0, stream>>>(W_in, wc, tw);
        int tr = (int)((L - 1) * 24 * 6 * 64);
        fmt_w11<<<(tr + 255) / 256, 256, 0, stream>>>(W_rs, wr, 24, tr);
        int tl = (int)(12 * 6 * 64);
        fmt_w11<<<(tl + 255) / 256, 256, 0, stream>>>(W_last, wl, 12, tl);
        xpose<<<dim3(T / 64, BATCH), 256, 0, stream>>>(x, xah, xal);
    }

    dim3 grid(T / NT, BATCH);   // 32 x 16 = 512 blocks = exactly 2 per CU
    dim3 block(512);

    _Float16* curh = xah; _Float16* curl = xal;
    _Float16* nxth = xbh; _Float16* nxtl = xbl;

    wnet_layer<true, false><<<grid, block, 0, stream>>>(
        curh, curl, nxth, nxtl, mask,
        wc, b_in, wr, b_rs, o);
    { _Float16* t1 = curh; curh = nxth; nxth = t1;
      _Float16* t2 = curl; curl = nxtl; nxtl = t2; }

    for (int i = 1; i < L - 1; ++i) {
        wnet_layer<false, false><<<grid, block, 0, stream>>>(
            curh, curl, nxth, nxtl, mask,
            wc + (size_t)i * WIN_STRIDE, b_in + (size_t)i * 2 * C,
            wr + (size_t)i * WRS_STRIDE, b_rs + (size_t)i * 2 * C, o);
        { _Float16* t1 = curh; curh = nxth; nxth = t1;
          _Float16* t2 = curl; curl = nxtl; nxtl = t2; }
    }

    wnet_layer<false, true><<<grid, block, 0, stream>>>(
        curh, curl, nullptr, nullptr, mask,
        wc + (size_t)(L - 1) * WIN_STRIDE, b_in + (size_t)(L - 1) * 2 * C,
        wl, b_last, o);
}

// Round 14
// 1339.443 us; speedup vs baseline: 6.9304x; 6.9304x over previous
//
#include <hip/hip_runtime.h>
#include <hip/hip_bf16.h>

#define C 192
#define T 4096
#define L 16
#define BATCH 16
#define NT 64          // t-positions per block
#define XR 72          // x tile rows incl. halo 4+4
#define CPAD 200       // padded channel stride in LDS (halfs) -> 400B rows

#define CONV_TAP_STRIDE 73728   // elems: 24*6*512
#define MT_STRIDE       3072    // 6*512
#define ICC_STRIDE      512

typedef __attribute__((ext_vector_type(8))) _Float16 half8;
typedef __attribute__((ext_vector_type(4))) _Float16 half4;
typedef __attribute__((ext_vector_type(4))) float f32x4;

__device__ __forceinline__ float gatefn(float x1, float x2) {
    float ax = fabsf(x1);
    float e  = __expf(-2.f * ax);
    float th = __builtin_copysignf((1.f - e) / (1.f + e), x1);
    float sg = 1.f / (1.f + __expf(-x2));
    return th * sg;
}

// ---- weight pre-format, single fp16 plane, MFMA A-frag order ----
__global__ __launch_bounds__(256)
void fmt_win(const float* __restrict__ W, _Float16* __restrict__ dst, int total) {
    int gid = blockIdx.x * 256 + threadIdx.x;
    if (gid >= total) return;
    int lane = gid & 63; int r = gid >> 6;
    int icc = r % 6; r /= 6;
    int mt  = r % 24; r /= 24;
    int tap = r % 5;  int l = r / 5;
    int oc  = mt * 16 + (lane & 15);
    int ic0 = icc * 32 + (lane >> 4) * 8;
    const float* s = W + ((size_t)((l * 384 + oc) * 192 + ic0)) * 5 + tap;
    half8 v;
    #pragma unroll
    for (int i = 0; i < 8; ++i) v[i] = (_Float16)s[(size_t)i * 5];
    *reinterpret_cast<half8*>(dst + (size_t)gid * 8) = v;
}

__global__ __launch_bounds__(256)
void fmt_w11(const float* __restrict__ W, _Float16* __restrict__ dst, int mtc, int total) {
    int gid = blockIdx.x * 256 + threadIdx.x;
    if (gid >= total) return;
    int lane = gid & 63; int r = gid >> 6;
    int icc = r % 6; r /= 6;
    int mt  = r % mtc; int l = r / mtc;
    int oc  = mt * 16 + (lane & 15);
    int ic0 = icc * 32 + (lane >> 4) * 8;
    const float* s = W + (size_t)(l * (mtc * 16) + oc) * 192 + ic0;
    half8 v;
    #pragma unroll
    for (int i = 0; i < 8; ++i) v[i] = (_Float16)s[i];
    *reinterpret_cast<half8*>(dst + (size_t)gid * 8) = v;
}

// ---- one-time transpose+split: x fp32 [b][c][t] -> fp16 hi/lo planes [b][t][c] ----
// Master = hi+lo (fp16 Dekker pair, ~22-bit): storage adds no error source.
__global__ __launch_bounds__(256)
void xpose(const float* __restrict__ x, _Float16* __restrict__ xh, _Float16* __restrict__ xl)
{
    __shared__ float tile[C][65];
    const int t0 = blockIdx.x * 64;
    const int b  = blockIdx.y;
    const float* xg = x + (size_t)b * C * T;
    for (int idx = threadIdx.x; idx < C * 16; idx += 256) {
        int ch = idx & 15, c = idx >> 4;
        f32x4 v = *reinterpret_cast<const f32x4*>(xg + (size_t)c * T + t0 + ch * 4);
        #pragma unroll
        for (int q = 0; q < 4; ++q) tile[c][ch * 4 + q] = v[q];
    }
    __syncthreads();
    for (int idx = threadIdx.x; idx < 64 * 24; idx += 256) {
        int cc = idx % 24, t = idx / 24;
        half8 h8, l8;
        #pragma unroll
        for (int i = 0; i < 8; ++i) {
            float v = tile[cc * 8 + i][t];
            _Float16 h = (_Float16)v;
            h8[i] = h;
            l8[i] = (_Float16)(v - (float)h);
        }
        size_t off = (size_t)b * T * C + (size_t)(t0 + t) * C + cc * 8;
        *reinterpret_cast<half8*>(xh + off) = h8;
        *reinterpret_cast<half8*>(xl + off) = l8;
    }
}

// ---- fused WaveNet layer, single-pass fp16 MFMA ----
// 4 waves (256 thr): wm=wid owns 6 mt (3 gate pairs) x p=4 nt-subtiles.
// 28.8 KB LDS (hi plane only) -> multiple de-phased blocks/CU.
// launch_bounds(256,2): 256-reg cap -- this structure spills below ~192 (r13).
template<bool FIRST, bool LAST>
__global__ __launch_bounds__(256, 2)
void wnet_layer(const _Float16* __restrict__ xhin, const _Float16* __restrict__ xlin,
                _Float16* __restrict__ xhout, _Float16* __restrict__ xlout,
                const float* __restrict__ mask,
                const _Float16* __restrict__ wc,   // conv weights fp16
                const float* __restrict__ bc,
                const _Float16* __restrict__ wr,   // 1x1 weights fp16
                const float* __restrict__ br,
                float* __restrict__ o)
{
    __shared__ __align__(16) _Float16 xhi[XR * CPAD];   // 28,800 B

    const int tid = threadIdx.x;
    const int t0  = blockIdx.x * NT;
    const int b   = blockIdx.y;

    // ---- stage hi plane: pure 16B vector copies ----
    {
        const _Float16* gh = xhin + (size_t)b * T * C;
        for (int idx = tid; idx < XR * 24; idx += 256) {
            int chunk = idx % 24;
            int r     = idx / 24;
            int t = t0 - 4 + r;
            half8 v = {};
            if (t >= 0 && t < T)
                v = *reinterpret_cast<const half8*>(gh + (size_t)t * C + chunk * 8);
            *reinterpret_cast<half8*>(&xhi[r * CPAD + chunk * 8]) = v;
        }
    }
    __syncthreads();

    const int lane = tid & 63;
    const int wm   = tid >> 6;      // 0..3
    const int col  = lane & 15;
    const int sg   = lane >> 4;

    int wbase[6];
    #pragma unroll
    for (int q = 0; q < 6; ++q) {
        int h = q / 3, j = q % 3;
        int mt = h * 12 + wm * 3 + j;
        wbase[q] = mt * MT_STRIDE + lane * 8;
    }

    // ---- conv K5, single pass, dbuf weight pipeline ----
    f32x4 acc[3][2][4];
    #pragma unroll
    for (int j = 0; j < 3; ++j)
    #pragma unroll
    for (int h = 0; h < 2; ++h) {
        f32x4 bv = *reinterpret_cast<const f32x4*>(bc + (h * 12 + wm * 3 + j) * 16 + sg * 4);
        #pragma unroll
        for (int p = 0; p < 4; ++p) acc[j][h][p] = bv;
    }

    half8 hA[6], hB[6];
    #pragma unroll
    for (int q = 0; q < 6; ++q)
        hA[q] = *reinterpret_cast<const half8*>(wc + wbase[q]);   // (tap0,icc0)

    auto convstep = [&](int icc, half8 (&curH)[6], half8 (&nxtH)[6],
                        size_t tapoff, size_t ntapoff, int tap) {
        const size_t coff = tapoff + (size_t)icc * ICC_STRIDE;
        const size_t noff = (icc == 5) ? ntapoff : coff + ICC_STRIDE;
        #pragma unroll
        for (int q = 0; q < 6; ++q)
            nxtH[q] = *reinterpret_cast<const half8*>(wc + noff + wbase[q]);
        half8 bh[4];
        #pragma unroll
        for (int p = 0; p < 4; ++p) {
            int off = (p * 16 + col + tap + 2) * CPAD + icc * 32 + sg * 8;
            bh[p] = *reinterpret_cast<const half8*>(&xhi[off]);
        }
        __builtin_amdgcn_sched_barrier(0);
        __builtin_amdgcn_s_setprio(1);
        #pragma unroll
        for (int h = 0; h < 2; ++h)
        #pragma unroll
        for (int j = 0; j < 3; ++j)
        #pragma unroll
        for (int p = 0; p < 4; ++p)
            acc[j][h][p] = __builtin_amdgcn_mfma_f32_16x16x32_f16(
                curH[h * 3 + j], bh[p], acc[j][h][p], 0, 0, 0);
        __builtin_amdgcn_s_setprio(0);
    };

    for (int tap = 0; tap < 5; ++tap) {
        const size_t tapoff  = (size_t)tap * CONV_TAP_STRIDE;
        const size_t ntapoff = (size_t)(tap < 4 ? tap + 1 : 4) * CONV_TAP_STRIDE;
        #pragma unroll
        for (int ih = 0; ih < 3; ++ih) {
            convstep(2 * ih,     hA, hB, tapoff, ntapoff, tap);
            convstep(2 * ih + 1, hB, hA, tapoff, ntapoff, tap);
        }
    }

    // ---- residual x-hi pre-read from LDS (before acts overwrite) ----
    half4 xresh[3][4];
    if constexpr (!LAST) {
        #pragma unroll
        for (int p = 0; p < 4; ++p) {
            const int row = p * 16 + col + 4;
            #pragma unroll
            for (int j = 0; j < 3; ++j) {
                const int ch = (wm * 3 + j) * 16 + sg * 4;
                xresh[j][p] = *reinterpret_cast<const half4*>(&xhi[row * CPAD + ch]);
            }
        }
    }
    __syncthreads();   // conv + residual LDS reads done before acts overwrite

    // ---- gate -> acts fp16 (reuse xhi rows [0,NT)) ----
    #pragma unroll
    for (int j = 0; j < 3; ++j)
    #pragma unroll
    for (int p = 0; p < 4; ++p) {
        const int tt = p * 16 + col;
        const int ch = (wm * 3 + j) * 16 + sg * 4;
        half4 av;
        #pragma unroll
        for (int i = 0; i < 4; ++i)
            av[i] = (_Float16)gatefn(acc[j][0][p][i], acc[j][1][p][i]);
        *reinterpret_cast<half4*>(&xhi[tt * CPAD + ch]) = av;
    }
    __syncthreads();

    // ---- 1x1 single pass, two sequential h-phases, dbuf pipeline ----
    const float* mb = mask + (size_t)b * T;
    float mv[4];
    #pragma unroll
    for (int p = 0; p < 4; ++p) mv[p] = mb[t0 + p * 16 + col];

    constexpr int HN = LAST ? 1 : 2;
    #pragma unroll
    for (int h = 0; h < HN; ++h) {
        f32x4 a2[3][4];
        #pragma unroll
        for (int j = 0; j < 3; ++j) {
            f32x4 bv = *reinterpret_cast<const f32x4*>(br + (h * 12 + wm * 3 + j) * 16 + sg * 4);
            #pragma unroll
            for (int p = 0; p < 4; ++p) a2[j][p] = bv;
        }
        const int* wb = wbase + h * 3;

        half8 rA[3], rB[3];
        #pragma unroll
        for (int q = 0; q < 3; ++q)
            rA[q] = *reinterpret_cast<const half8*>(wr + wb[q]);   // icc=0

        auto r1step = [&](int icc, half8 (&cur)[3], half8 (&nxt)[3]) {
            const size_t noff = (size_t)(icc < 5 ? icc + 1 : 5) * ICC_STRIDE;
            #pragma unroll
            for (int q = 0; q < 3; ++q)
                nxt[q] = *reinterpret_cast<const half8*>(wr + noff + wb[q]);
            half8 bah[4];
            #pragma unroll
            for (int p = 0; p < 4; ++p) {
                int off = (p * 16 + col) * CPAD + icc * 32 + sg * 8;
                bah[p] = *reinterpret_cast<const half8*>(&xhi[off]);
            }
            __builtin_amdgcn_sched_barrier(0);
            __builtin_amdgcn_s_setprio(1);
            #pragma unroll
            for (int j = 0; j < 3; ++j)
            #pragma unroll
            for (int p = 0; p < 4; ++p)
                a2[j][p] = __builtin_amdgcn_mfma_f32_16x16x32_f16(
                    cur[j], bah[p], a2[j][p], 0, 0, 0);
            __builtin_amdgcn_s_setprio(0);
        };

        #pragma unroll
        for (int ih = 0; ih < 3; ++ih) {
            r1step(2 * ih,     rA, rB);
            r1step(2 * ih + 1, rB, rA);
        }

        // ---- mini-epilogue for this phase ----
        #pragma unroll
        for (int p = 0; p < 4; ++p) {
            const int tt = p * 16 + col;
            const int t  = t0 + tt;
            #pragma unroll
            for (int j = 0; j < 3; ++j) {
                const int ch = (wm * 3 + j) * 16 + sg * 4;
                if constexpr (LAST) {
                    float* op = o + ((size_t)b * C + ch) * T + t;
                    #pragma unroll
                    for (int i = 0; i < 4; ++i)
                        op[(size_t)i * T] = (op[(size_t)i * T] + a2[j][p][i]) * mv[p];
                } else if (h == 0) {
                    // residual x update: master = hi(LDS-preread) + lo(global)
                    size_t off = (size_t)b * T * C + (size_t)t * C + ch;
                    half4 xl4 = *reinterpret_cast<const half4*>(xlin + off);
                    half4 h4, l4;
                    #pragma unroll
                    for (int i = 0; i < 4; ++i) {
                        float xm = (float)xresh[j][p][i] + (float)xl4[i];
                        float nx = (xm + a2[j][p][i]) * mv[p];
                        _Float16 hh = (_Float16)nx;
                        h4[i] = hh;
                        l4[i] = (_Float16)(nx - (float)hh);
                    }
                    *reinterpret_cast<half4*>(xhout + off) = h4;
                    *reinterpret_cast<half4*>(xlout + off) = l4;
                } else {
                    float* op = o + ((size_t)b * C + ch) * T + t;
                    #pragma unroll
                    for (int i = 0; i < 4; ++i) {
                        if constexpr (FIRST) op[(size_t)i * T] = a2[j][p][i];
                        else                 op[(size_t)i * T] += a2[j][p][i];
                    }
                }
            }
        }
    }
}

#define WIN_STRIDE ((size_t)5 * 24 * 6 * 64 * 8)
#define WRS_STRIDE ((size_t)24 * 6 * 64 * 8)

extern "C" void kernel_launch(void* const* d_in, const int* in_sizes, int n_in,
                              void* d_out, int out_size, void* d_ws, size_t ws_size,
                              hipStream_t stream)
{
    const float* x      = (const float*)d_in[0];
    const float* mask   = (const float*)d_in[1];
    const float* W_in   = (const float*)d_in[2];
    const float* b_in   = (const float*)d_in[3];
    const float* W_rs   = (const float*)d_in[4];
    const float* b_rs   = (const float*)d_in[5];
    const float* W_last = (const float*)d_in[6];
    const float* b_last = (const float*)d_in[7];
    float* o = (float*)d_out;

    const size_t WIN_N = (size_t)L * WIN_STRIDE;
    const size_t WRS_N = (size_t)(L - 1) * WRS_STRIDE;
    const size_t WL_N  = (size_t)12 * 6 * 64 * 8;
    const size_t P     = (size_t)BATCH * T * C;      // plane elems
    _Float16* wc  = (_Float16*)d_ws;
    _Float16* wr  = wc + WIN_N;
    _Float16* wl  = wr + WRS_N;
    _Float16* xah = wl + WL_N;
    _Float16* xal = xah + P;
    _Float16* xbh = xal + P;
    _Float16* xbl = xbh + P;

    {
        int tw = (int)(L * 5 * 24 * 6 * 64);
        fmt_win<<<(tw + 255) / 256, 256, 0, stream>>>(W_in, wc, tw);
        int tr = (int)((L - 1) * 24 * 6 * 64);
        fmt_w11<<<(tr + 255) / 256, 256, 0, stream>>>(W_rs, wr, 24, tr);
        int tl = (int)(12 * 6 * 64);
        fmt_w11<<<(tl + 255) / 256, 256, 0, stream>>>(W_last, wl, 12, tl);
        xpose<<<dim3(T / 64, BATCH), 256, 0, stream>>>(x, xah, xal);
    }

    dim3 grid(T / NT, BATCH);
    dim3 block(256);

    _Float16* curh = xah; _Float16* curl = xal;
    _Float16* nxth = xbh; _Float16* nxtl = xbl;

    wnet_layer<true, false><<<grid, block, 0, stream>>>(
        curh, curl, nxth, nxtl, mask,
        wc, b_in, wr, b_rs, o);
    { _Float16* t1 = curh; curh = nxth; nxth = t1;
      _Float16* t2 = curl; curl = nxtl; nxtl = t2; }

    for (int i = 1; i < L - 1; ++i) {
        wnet_layer<false, false><<<grid, block, 0, stream>>>(
            curh, curl, nxth, nxtl, mask,
            wc + (size_t)i * WIN_STRIDE, b_in + (size_t)i * 2 * C,
            wr + (size_t)i * WRS_STRIDE, b_rs + (size_t)i * 2 * C, o);
        { _Float16* t1 = curh; curh = nxth; nxth = t1;
          _Float16* t2 = curl; curl = nxtl; nxtl = t2; }
    }

    wnet_layer<false, true><<<grid, block, 0, stream>>>(
        curh, curl, nullptr, nullptr, mask,
        wc + (size_t)(L - 1) * WIN_STRIDE, b_in + (size_t)(L - 1) * 2 * C,
        wl, b_last, o);
}

// Round 15
// 1334.323 us; speedup vs baseline: 6.9570x; 1.0038x over previous
//
#include <hip/hip_runtime.h>
#include <hip/hip_bf16.h>

#define C 192
#define T 4096
#define L 16
#define BATCH 16
#define NT 64          // t-positions per block
#define XR 72          // x tile rows incl. halo 4+4
#define CPAD 200       // padded channel stride in LDS (halfs) -> 400B rows

#define CONV_TAP_STRIDE 73728   // elems: 24*6*512
#define MT_STRIDE       3072    // 6*512
#define ICC_STRIDE      512

typedef __attribute__((ext_vector_type(8))) _Float16 half8;
typedef __attribute__((ext_vector_type(4))) _Float16 half4;
typedef __attribute__((ext_vector_type(4))) float f32x4;

__device__ __forceinline__ float gatefn(float x1, float x2) {
    float ax = fabsf(x1);
    float e  = __expf(-2.f * ax);
    float th = __builtin_copysignf((1.f - e) / (1.f + e), x1);
    float sg = 1.f / (1.f + __expf(-x2));
    return th * sg;
}

// ---- weight pre-format, single fp16 plane, MFMA A-frag order ----
__global__ __launch_bounds__(256)
void fmt_win(const float* __restrict__ W, _Float16* __restrict__ dst, int total) {
    int gid = blockIdx.x * 256 + threadIdx.x;
    if (gid >= total) return;
    int lane = gid & 63; int r = gid >> 6;
    int icc = r % 6; r /= 6;
    int mt  = r % 24; r /= 24;
    int tap = r % 5;  int l = r / 5;
    int oc  = mt * 16 + (lane & 15);
    int ic0 = icc * 32 + (lane >> 4) * 8;
    const float* s = W + ((size_t)((l * 384 + oc) * 192 + ic0)) * 5 + tap;
    half8 v;
    #pragma unroll
    for (int i = 0; i < 8; ++i) v[i] = (_Float16)s[(size_t)i * 5];
    *reinterpret_cast<half8*>(dst + (size_t)gid * 8) = v;
}

__global__ __launch_bounds__(256)
void fmt_w11(const float* __restrict__ W, _Float16* __restrict__ dst, int mtc, int total) {
    int gid = blockIdx.x * 256 + threadIdx.x;
    if (gid >= total) return;
    int lane = gid & 63; int r = gid >> 6;
    int icc = r % 6; r /= 6;
    int mt  = r % mtc; int l = r / mtc;
    int oc  = mt * 16 + (lane & 15);
    int ic0 = icc * 32 + (lane >> 4) * 8;
    const float* s = W + (size_t)(l * (mtc * 16) + oc) * 192 + ic0;
    half8 v;
    #pragma unroll
    for (int i = 0; i < 8; ++i) v[i] = (_Float16)s[i];
    *reinterpret_cast<half8*>(dst + (size_t)gid * 8) = v;
}

// ---- one-time transpose+split: x fp32 [b][c][t] -> fp16 hi/lo planes [b][t][c] ----
__global__ __launch_bounds__(256)
void xpose(const float* __restrict__ x, _Float16* __restrict__ xh, _Float16* __restrict__ xl)
{
    __shared__ float tile[C][65];
    const int t0 = blockIdx.x * 64;
    const int b  = blockIdx.y;
    const float* xg = x + (size_t)b * C * T;
    for (int idx = threadIdx.x; idx < C * 16; idx += 256) {
        int ch = idx & 15, c = idx >> 4;
        f32x4 v = *reinterpret_cast<const f32x4*>(xg + (size_t)c * T + t0 + ch * 4);
        #pragma unroll
        for (int q = 0; q < 4; ++q) tile[c][ch * 4 + q] = v[q];
    }
    __syncthreads();
    for (int idx = threadIdx.x; idx < 64 * 24; idx += 256) {
        int cc = idx % 24, t = idx / 24;
        half8 h8, l8;
        #pragma unroll
        for (int i = 0; i < 8; ++i) {
            float v = tile[cc * 8 + i][t];
            _Float16 h = (_Float16)v;
            h8[i] = h;
            l8[i] = (_Float16)(v - (float)h);
        }
        size_t off = (size_t)b * T * C + (size_t)(t0 + t) * C + cc * 8;
        *reinterpret_cast<half8*>(xh + off) = h8;
        *reinterpret_cast<half8*>(xl + off) = l8;
    }
}

// ---- fused WaveNet layer, single-pass fp16 MFMA ----
// 4 waves (256 thr): wm=wid owns 6 mt (3 gate pairs) x p=4 nt-subtiles.
// LDS: xhi (XR rows, halo) + xlo (NT rows, epilogue residual) = 54.4 KB.
// Unified-reg cap (~224/wave) already limits to 2 waves/SIMD, so the extra
// LDS is free. 1x1 is a single merged loop over both h-halves.
template<bool FIRST, bool LAST>
__global__ __launch_bounds__(256, 2)
void wnet_layer(const _Float16* __restrict__ xhin, const _Float16* __restrict__ xlin,
                _Float16* __restrict__ xhout, _Float16* __restrict__ xlout,
                const float* __restrict__ mask,
                const _Float16* __restrict__ wc,   // conv weights fp16
                const float* __restrict__ bc,
                const _Float16* __restrict__ wr,   // 1x1 weights fp16
                const float* __restrict__ br,
                float* __restrict__ o)
{
    __shared__ __align__(16) _Float16 xhi[XR * CPAD];   // 28,800 B
    __shared__ __align__(16) _Float16 xlo[NT * CPAD];   // 25,600 B

    const int tid = threadIdx.x;
    const int t0  = blockIdx.x * NT;
    const int b   = blockIdx.y;

    // ---- stage hi plane (halo) + lo plane (interior, epilogue-only) ----
    {
        const _Float16* gh = xhin + (size_t)b * T * C;
        for (int idx = tid; idx < XR * 24; idx += 256) {
            int chunk = idx % 24;
            int r     = idx / 24;
            int t = t0 - 4 + r;
            half8 v = {};
            if (t >= 0 && t < T)
                v = *reinterpret_cast<const half8*>(gh + (size_t)t * C + chunk * 8);
            *reinterpret_cast<half8*>(&xhi[r * CPAD + chunk * 8]) = v;
        }
        if constexpr (!LAST) {
            const _Float16* gl = xlin + (size_t)b * T * C;
            for (int idx = tid; idx < NT * 24; idx += 256) {
                int chunk = idx % 24;
                int r     = idx / 24;
                half8 v = *reinterpret_cast<const half8*>(
                    gl + (size_t)(t0 + r) * C + chunk * 8);
                *reinterpret_cast<half8*>(&xlo[r * CPAD + chunk * 8]) = v;
            }
        }
    }
    __syncthreads();

    const int lane = tid & 63;
    const int wm   = tid >> 6;      // 0..3
    const int col  = lane & 15;
    const int sg   = lane >> 4;

    int wbase[6];
    #pragma unroll
    for (int q = 0; q < 6; ++q) {
        int h = q / 3, j = q % 3;
        int mt = h * 12 + wm * 3 + j;
        wbase[q] = mt * MT_STRIDE + lane * 8;
    }

    // ---- conv K5, single pass, dbuf weight pipeline ----
    f32x4 acc[3][2][4];
    #pragma unroll
    for (int j = 0; j < 3; ++j)
    #pragma unroll
    for (int h = 0; h < 2; ++h) {
        f32x4 bv = *reinterpret_cast<const f32x4*>(bc + (h * 12 + wm * 3 + j) * 16 + sg * 4);
        #pragma unroll
        for (int p = 0; p < 4; ++p) acc[j][h][p] = bv;
    }

    half8 hA[6], hB[6];
    #pragma unroll
    for (int q = 0; q < 6; ++q)
        hA[q] = *reinterpret_cast<const half8*>(wc + wbase[q]);   // (tap0,icc0)

    auto convstep = [&](int icc, half8 (&curH)[6], half8 (&nxtH)[6],
                        size_t tapoff, size_t ntapoff, int tap) {
        const size_t coff = tapoff + (size_t)icc * ICC_STRIDE;
        const size_t noff = (icc == 5) ? ntapoff : coff + ICC_STRIDE;
        #pragma unroll
        for (int q = 0; q < 6; ++q)
            nxtH[q] = *reinterpret_cast<const half8*>(wc + noff + wbase[q]);
        half8 bh[4];
        #pragma unroll
        for (int p = 0; p < 4; ++p) {
            int off = (p * 16 + col + tap + 2) * CPAD + icc * 32 + sg * 8;
            bh[p] = *reinterpret_cast<const half8*>(&xhi[off]);
        }
        __builtin_amdgcn_sched_barrier(0);
        __builtin_amdgcn_s_setprio(1);
        #pragma unroll
        for (int h = 0; h < 2; ++h)
        #pragma unroll
        for (int j = 0; j < 3; ++j)
        #pragma unroll
        for (int p = 0; p < 4; ++p)
            acc[j][h][p] = __builtin_amdgcn_mfma_f32_16x16x32_f16(
                curH[h * 3 + j], bh[p], acc[j][h][p], 0, 0, 0);
        __builtin_amdgcn_s_setprio(0);
    };

    for (int tap = 0; tap < 5; ++tap) {
        const size_t tapoff  = (size_t)tap * CONV_TAP_STRIDE;
        const size_t ntapoff = (size_t)(tap < 4 ? tap + 1 : 4) * CONV_TAP_STRIDE;
        #pragma unroll
        for (int ih = 0; ih < 3; ++ih) {
            convstep(2 * ih,     hA, hB, tapoff, ntapoff, tap);
            convstep(2 * ih + 1, hB, hA, tapoff, ntapoff, tap);
        }
    }

    // ---- residual x-hi pre-read from LDS (before acts overwrite) ----
    half4 xresh[3][4];
    if constexpr (!LAST) {
        #pragma unroll
        for (int p = 0; p < 4; ++p) {
            const int row = p * 16 + col + 4;
            #pragma unroll
            for (int j = 0; j < 3; ++j) {
                const int ch = (wm * 3 + j) * 16 + sg * 4;
                xresh[j][p] = *reinterpret_cast<const half4*>(&xhi[row * CPAD + ch]);
            }
        }
    }
    __syncthreads();   // conv + residual LDS reads done before acts overwrite

    // ---- gate -> acts fp16 (reuse xhi rows [0,NT)) ----
    #pragma unroll
    for (int j = 0; j < 3; ++j)
    #pragma unroll
    for (int p = 0; p < 4; ++p) {
        const int tt = p * 16 + col;
        const int ch = (wm * 3 + j) * 16 + sg * 4;
        half4 av;
        #pragma unroll
        for (int i = 0; i < 4; ++i)
            av[i] = (_Float16)gatefn(acc[j][0][p][i], acc[j][1][p][i]);
        *reinterpret_cast<half4*>(&xhi[tt * CPAD + ch]) = av;
    }
    __syncthreads();

    // ---- 1x1 single pass, merged h-halves, dbuf pipeline ----
    const float* mb = mask + (size_t)b * T;
    float mv[4];
    #pragma unroll
    for (int p = 0; p < 4; ++p) mv[p] = mb[t0 + p * 16 + col];

    constexpr int HN = LAST ? 1 : 2;
    constexpr int NQ = HN * 3;
    f32x4 a2[3][HN][4];
    #pragma unroll
    for (int j = 0; j < 3; ++j)
    #pragma unroll
    for (int h = 0; h < HN; ++h) {
        f32x4 bv = *reinterpret_cast<const f32x4*>(br + (h * 12 + wm * 3 + j) * 16 + sg * 4);
        #pragma unroll
        for (int p = 0; p < 4; ++p) a2[j][h][p] = bv;
    }

    half8 rA[NQ], rB[NQ];
    #pragma unroll
    for (int q = 0; q < NQ; ++q)
        rA[q] = *reinterpret_cast<const half8*>(wr + wbase[q]);   // icc=0

    auto r1step = [&](int icc, half8 (&cur)[NQ], half8 (&nxt)[NQ]) {
        const size_t noff = (size_t)(icc < 5 ? icc + 1 : 5) * ICC_STRIDE;
        #pragma unroll
        for (int q = 0; q < NQ; ++q)
            nxt[q] = *reinterpret_cast<const half8*>(wr + noff + wbase[q]);
        half8 bah[4];
        #pragma unroll
        for (int p = 0; p < 4; ++p) {
            int off = (p * 16 + col) * CPAD + icc * 32 + sg * 8;
            bah[p] = *reinterpret_cast<const half8*>(&xhi[off]);
        }
        __builtin_amdgcn_sched_barrier(0);
        __builtin_amdgcn_s_setprio(1);
        #pragma unroll
        for (int h = 0; h < HN; ++h)
        #pragma unroll
        for (int j = 0; j < 3; ++j)
        #pragma unroll
        for (int p = 0; p < 4; ++p)
            a2[j][h][p] = __builtin_amdgcn_mfma_f32_16x16x32_f16(
                cur[h * 3 + j], bah[p], a2[j][h][p], 0, 0, 0);
        __builtin_amdgcn_s_setprio(0);
    };

    #pragma unroll
    for (int ih = 0; ih < 3; ++ih) {
        r1step(2 * ih,     rA, rB);
        r1step(2 * ih + 1, rB, rA);
    }

    // ---- epilogue (single pass) ----
    #pragma unroll
    for (int p = 0; p < 4; ++p) {
        const int tt = p * 16 + col;
        const int t  = t0 + tt;
        #pragma unroll
        for (int j = 0; j < 3; ++j) {
            const int ch = (wm * 3 + j) * 16 + sg * 4;
            if constexpr (LAST) {
                float* op = o + ((size_t)b * C + ch) * T + t;
                #pragma unroll
                for (int i = 0; i < 4; ++i)
                    op[(size_t)i * T] = (op[(size_t)i * T] + a2[j][0][p][i]) * mv[p];
            } else {
                // residual x update: master = hi(pre-read) + lo(LDS, coalesced-staged)
                size_t off = (size_t)b * T * C + (size_t)t * C + ch;
                half4 xl4 = *reinterpret_cast<const half4*>(&xlo[tt * CPAD + ch]);
                half4 h4, l4;
                #pragma unroll
                for (int i = 0; i < 4; ++i) {
                    float xm = (float)xresh[j][p][i] + (float)xl4[i];
                    float nx = (xm + a2[j][0][p][i]) * mv[p];
                    _Float16 hh = (_Float16)nx;
                    h4[i] = hh;
                    l4[i] = (_Float16)(nx - (float)hh);
                }
                *reinterpret_cast<half4*>(xhout + off) = h4;
                *reinterpret_cast<half4*>(xlout + off) = l4;
                // skip accumulation
                float* op = o + ((size_t)b * C + ch) * T + t;
                #pragma unroll
                for (int i = 0; i < 4; ++i) {
                    if constexpr (FIRST) op[(size_t)i * T] = a2[j][1][p][i];
                    else                 op[(size_t)i * T] += a2[j][1][p][i];
                }
            }
        }
    }
}

#define WIN_STRIDE ((size_t)5 * 24 * 6 * 64 * 8)
#define WRS_STRIDE ((size_t)24 * 6 * 64 * 8)

extern "C" void kernel_launch(void* const* d_in, const int* in_sizes, int n_in,
                              void* d_out, int out_size, void* d_ws, size_t ws_size,
                              hipStream_t stream)
{
    const float* x      = (const float*)d_in[0];
    const float* mask   = (const float*)d_in[1];
    const float* W_in   = (const float*)d_in[2];
    const float* b_in   = (const float*)d_in[3];
    const float* W_rs   = (const float*)d_in[4];
    const float* b_rs   = (const float*)d_in[5];
    const float* W_last = (const float*)d_in[6];
    const float* b_last = (const float*)d_in[7];
    float* o = (float*)d_out;

    const size_t WIN_N = (size_t)L * WIN_STRIDE;
    const size_t WRS_N = (size_t)(L - 1) * WRS_STRIDE;
    const size_t WL_N  = (size_t)12 * 6 * 64 * 8;
    const size_t P     = (size_t)BATCH * T * C;      // plane elems
    _Float16* wc  = (_Float16*)d_ws;
    _Float16* wr  = wc + WIN_N;
    _Float16* wl  = wr + WRS_N;
    _Float16* xah = wl + WL_N;
    _Float16* xal = xah + P;
    _Float16* xbh = xal + P;
    _Float16* xbl = xbh + P;

    {
        int tw = (int)(L * 5 * 24 * 6 * 64);
        fmt_win<<<(tw + 255) / 256, 256, 0, stream>>>(W_in, wc, tw);
        int tr = (int)((L - 1) * 24 * 6 * 64);
        fmt_w11<<<(tr + 255) / 256, 256, 0, stream>>>(W_rs, wr, 24, tr);
        int tl = (int)(12 * 6 * 64);
        fmt_w11<<<(tl + 255) / 256, 256, 0, stream>>>(W_last, wl, 12, tl);
        xpose<<<dim3(T / 64, BATCH), 256, 0, stream>>>(x, xah, xal);
    }

    dim3 grid(T / NT, BATCH);
    dim3 block(256);

    _Float16* curh = xah; _Float16* curl = xal;
    _Float16* nxth = xbh; _Float16* nxtl = xbl;

    wnet_layer<true, false><<<grid, block, 0, stream>>>(
        curh, curl, nxth, nxtl, mask,
        wc, b_in, wr, b_rs, o);
    { _Float16* t1 = curh; curh = nxth; nxth = t1;
      _Float16* t2 = curl; curl = nxtl; nxtl = t2; }

    for (int i = 1; i < L - 1; ++i) {
        wnet_layer<false, false><<<grid, block, 0, stream>>>(
            curh, curl, nxth, nxtl, mask,
            wc + (size_t)i * WIN_STRIDE, b_in + (size_t)i * 2 * C,
            wr + (size_t)i * WRS_STRIDE, b_rs + (size_t)i * 2 * C, o);
        { _Float16* t1 = curh; curh = nxth; nxth = t1;
          _Float16* t2 = curl; curl = nxtl; nxtl = t2; }
    }

    wnet_layer<false, true><<<grid, block, 0, stream>>>(
        curh, curl, nullptr, nullptr, mask,
        wc + (size_t)(L - 1) * WIN_STRIDE, b_in + (size_t)(L - 1) * 2 * C,
        wl, b_last, o);
}